// Round 5
// baseline (573.746 us; speedup 1.0000x reference)
//
#include <hip/hip_runtime.h>

#define N_NODES 81920
#define N_EDGES 1310720
#define NG 256
#define D 64
#define TM 64
#define SA 65            // f32 LDS row stride (GEMM tiles / pull accumulators)
#define SB 33            // bf16x2 LDS row stride in push (2-way bank alias, free)
#define NB 320           // 256-thread node blocks covering N_NODES
#define NBLK 1280        // blocks of 64 nodes
#define BMW 2560         // bitmask words (81920/32)
#define HCHUNK 4096      // edges per build workgroup (NB*HCHUNK == N_EDGES)
#define EPT 16           // edges per thread in build (HCHUNK/256)
#define CAP0 1280        // layer-0 slab cap per DST block (mean ~582, sigma ~68)
#define CAP1 256         // layer-1 slab cap per SRC block (push path)
#define CAP2 64

typedef __attribute__((ext_vector_type(2))) short sbf2;

__device__ __forceinline__ bool tb(const unsigned* bm, int i) {
    return (bm[i >> 5] >> (i & 31)) & 1u;
}
__device__ __forceinline__ unsigned bf16rne(float f) {
    unsigned u = __float_as_uint(f);
    return (u + 0x7fffu + ((u >> 16) & 1u)) >> 16;
}
// fire-and-forget global->LDS stage: lane's 4B from gp -> ldsbase + lane*4
__device__ __forceinline__ void glds4(const unsigned* gp, unsigned* lp) {
    __builtin_amdgcn_global_load_lds(
        (const __attribute__((address_space(1))) unsigned*)gp,
        (__attribute__((address_space(3))) unsigned*)lp, 4, 0, 0);
}

// ---------------- init: zero bitmasks/indeg/counters, init slab cursors --------

__global__ __launch_bounds__(256) void init_ws(unsigned* __restrict__ bms,   // 3*BMW
                                               int* __restrict__ indeg,
                                               int* __restrict__ n01,
                                               int* __restrict__ cur0,
                                               int* __restrict__ cur1,
                                               int* __restrict__ cur2) {
    int t = blockIdx.x * 256 + threadIdx.x;          // grid NB -> 81920 threads
    if (t < 3 * BMW) bms[t] = 0u;
    indeg[t] = 0;
    if (t < 2) n01[t] = 0;
    if (t < NBLK) {
        cur0[t] = t * CAP0;
        cur1[t] = t * CAP1;
        cur2[t] = t * CAP2;
    }
}

// ---------------- x -> bf16x2 copy (halves the scattered gather bytes) ----------

__global__ __launch_bounds__(256) void x_to_bf16(const float2* __restrict__ x2,
                                                 unsigned* __restrict__ xb) {
    int t = blockIdx.x * 256 + threadIdx.x;          // grid 10240 -> 2.62M words
    float2 v = x2[t];
    xb[t] = bf16rne(v.x) | (bf16rne(v.y) << 16);
}

// ---------------- graph firsts + seed bm2/bm1 + zero the 256 f32 agg rows ----------

__global__ void ff_mark(const int* __restrict__ batch, int* __restrict__ fidx,
                        unsigned* __restrict__ bm2, unsigned* __restrict__ bm1,
                        float* __restrict__ aggf) {
    int i = blockIdx.x * 256 + threadIdx.x;          // grid NB
    int b = batch[i];
    if (i == 0 || batch[i - 1] != b) {
        fidx[b] = i;
        unsigned bit = 1u << (i & 31);
        atomicOr(&bm2[i >> 5], bit);
        atomicOr(&bm1[i >> 5], bit);
        float4* r = (float4*)&aggf[i * D];           // zero this output row (layer-2 agg)
        #pragma unroll
        for (int j = 0; j < 16; ++j) r[j] = make_float4(0.f, 0.f, 0.f, 0.f);
    }
}

// mark srcs of edges with dst-bit in bmD into bmS; optional OR-copy orsrc -> bmS
__global__ void mark_srcs_bm(const int* __restrict__ src, const int* __restrict__ dst,
                             const unsigned* __restrict__ bmD, unsigned* __restrict__ bmS,
                             const unsigned* __restrict__ orsrc) {
    if (orsrc && blockIdx.x == 0) {
        for (int w = threadIdx.x; w < BMW; w += 256)
            if (orsrc[w]) atomicOr(&bmS[w], orsrc[w]);
    }
    int e = blockIdx.x * 256 + threadIdx.x;
    if (e < N_EDGES && tb(bmD, dst[e])) {
        int s = src[e];
        atomicOr(&bmS[s >> 5], 1u << (s & 31));
    }
}

// ---------------- build: ONE edge stream, register-carried ranks, slab bucketing ----

__global__ __launch_bounds__(256) void build(const int* __restrict__ src,
                                             const int* __restrict__ dst,
                                             const unsigned* __restrict__ bm0,
                                             const unsigned* __restrict__ bm1,
                                             const unsigned* __restrict__ bm2,
                                             int* __restrict__ cur0,
                                             int* __restrict__ cur1,
                                             int* __restrict__ cur2,
                                             int* __restrict__ esp0,
                                             int* __restrict__ esp1,
                                             int* __restrict__ esp2,
                                             int* __restrict__ list1,
                                             int* __restrict__ n1) {
    __shared__ int h0[NBLK];      // per-DST-block count
    __shared__ int b0[NBLK];      // reserved base per dst block
    const int tid = threadIdx.x;
    const int e0  = blockIdx.x * HCHUNK;             // grid NB (320)

    for (int i = tid; i < NBLK; i += 256) h0[i] = 0;

    // list1 compaction for this WG's 256-node chunk (independent)
    {
        int i = blockIdx.x * 256 + tid;
        int lane = tid & 63;
        bool p1 = tb(bm1, i);
        unsigned long long b1 = __ballot(p1);
        int lt = __popcll(b1 & ((1ull << lane) - 1));
        int base = 0;
        if (lane == 0 && b1) base = atomicAdd(n1, __popcll(b1));
        base = __shfl(base, 0);
        if (p1) list1[base + lt] = i;
    }
    __syncthreads();

    int pk_r[EPT];
    int db_r[EPT];
    int rk_r[EPT];

    // pass A: stream edges once; count L0 in LDS, carry ranks in registers;
    // place rare L1/L2 directly
    #pragma unroll
    for (int j = 0; j < EPT; ++j) {
        int e = e0 + j * 256 + tid;                  // coalesced
        int d = dst[e];
        db_r[j] = -1;
        if (tb(bm0, d)) {
            int s  = src[e];
            int db = d >> 6;
            pk_r[j] = (s << 6) | (d & 63);           // pull format
            db_r[j] = db;
            rk_r[j] = atomicAdd(&h0[db], 1);         // LDS
            if (tb(bm1, d)) {
                int sb = s >> 6;
                int pk = (d << 6) | (s & 63);        // push format
                int p1 = atomicAdd(&cur1[sb], 1);    // rare (9%)
                if (p1 < sb * CAP1 + CAP1) esp1[p1] = pk;
                if (tb(bm2, d)) {
                    int p2 = atomicAdd(&cur2[sb], 1); // very rare (0.7%)
                    if (p2 < sb * CAP2 + CAP2) esp2[p2] = pk;
                }
            }
        }
    }
    __syncthreads();

    // bulk-reserve layer-0 slab chunks
    for (int i = tid; i < NBLK; i += 256) {
        int c = h0[i];
        b0[i] = c ? atomicAdd(&cur0[i], c) : 0;
    }
    __syncthreads();

    // pass B: place layer-0 edges from registers
    #pragma unroll
    for (int j = 0; j < EPT; ++j) {
        int db = db_r[j];
        if (db >= 0) {
            int pos = b0[db] + rk_r[j];
            if (pos < db * CAP0 + CAP0) esp0[pos] = pk_r[j];
        }
    }
}

// ---------------- layer 0 PULL: fire-and-forget gather via global_load_lds --------
// blockIdx = dst-block*2 + half (K-split). Per wave: process 64-edge superchunks as
// 2 batches of 32. Per batch: issue 16 global_load_lds (size 4) -- each stages TWO
// bf16 src rows (256 B) into wave-private LDS staging, zero result VGPRs, nothing
// blocks -- then ONE s_waitcnt vmcnt(0) + sched_barrier, then drain staging into the
// f32 LDS accumulator with ds_add. MLP comes from 16 outstanding stage-loads/wave x
// 16 waves/CU, not from the compiler's register scheduler (which refused: r2-r4).

__global__ __launch_bounds__(256, 4) void sage_pull_l0(
    const unsigned* __restrict__ xb, const int* __restrict__ cur,
    const int* __restrict__ esp, int* __restrict__ indeg,
    unsigned* __restrict__ aggb, unsigned* __restrict__ aggc)
{
    __shared__ float As[TM * SA];            // 16.6 KB acc (64 rows + count col 64)
    __shared__ unsigned St[4][32 * 32];      // 16 KB: per-wave 32-edge bf16 staging

    const int tid  = threadIdx.x;
    const int db   = blockIdx.x >> 1;                // dst block
    const int half = blockIdx.x & 1;
    const int base = db * TM;
    const int lane = tid & 63;
    const int w    = tid >> 6;
    unsigned* stw  = &St[w][0];

    for (int idx = tid; idx < TM * SA; idx += 256) As[idx] = 0.f;
    __syncthreads();

    const int s0  = db * CAP0;
    const int cnt = min(cur[db] - s0, CAP0);
    const int hb  = cnt >> 1;
    const int e0  = s0 + (half ? hb : 0);
    const int e1  = s0 + (half ? cnt : hb);
    const int n   = e1 - e0;

    if (n > 0) {
        const int chunk = (n + 3) >> 2;
        int e = e0 + w * chunk;
        const int ee = min(e + chunk, e1);
        const int g   = lane >> 4;               // drain: edge sub-index 0..3
        const int c   = (lane & 15) << 2;        // drain: f32 col 0,4,..,60
        const bool cl0 = (lane & 15) == 0;

        for (; e < ee; e += 64) {
            const int rem = ee - e;
            int pv = esp[min(e + lane, e1 - 1)];
            #pragma unroll
            for (int sub = 0; sub < 2; ++sub) {
                const int sb = sub << 5;
                if (sb >= rem) break;
                // ---- issue: 16 fire-and-forget stage loads (2 rows each) ----
                #pragma unroll
                for (int j = 0; j < 16; ++j) {
                    int ei = sb + (j << 1) + (lane >> 5);
                    int p  = __shfl(pv, ei);
                    if (ei < rem)
                        glds4(&xb[((p >> 6) << 5) + (lane & 31)], &stw[j << 6]);
                }
                __builtin_amdgcn_sched_barrier(0);
                asm volatile("s_waitcnt vmcnt(0)" ::: "memory");
                __builtin_amdgcn_sched_barrier(0);
                // ---- drain: 8 iters x 4 edges, unpack bf16 + ds_add ----
                #pragma unroll
                for (int it = 0; it < 8; ++it) {
                    int slot = (it << 2) + g;
                    int ei   = sb + slot;
                    uint2 dv = *(const uint2*)&stw[(slot << 5) + ((lane & 15) << 1)];
                    int p    = __shfl(pv, ei);
                    int dl   = p & 63;
                    if (ei < rem) {
                        atomicAdd(&As[dl * SA + c + 0], __uint_as_float(dv.x << 16));
                        atomicAdd(&As[dl * SA + c + 1], __uint_as_float(dv.x & 0xffff0000u));
                        atomicAdd(&As[dl * SA + c + 2], __uint_as_float(dv.y << 16));
                        atomicAdd(&As[dl * SA + c + 3], __uint_as_float(dv.y & 0xffff0000u));
                        if (cl0) atomicAdd(&As[dl * SA + 64], 1.0f);
                    }
                }
                __builtin_amdgcn_sched_barrier(0);
            }
        }
    }
    __syncthreads();

    unsigned* part = half ? aggc : aggb;
    for (int idx = tid; idx < TM * 32; idx += 256) {
        int m = idx >> 5, j = idx & 31;
        unsigned lo = bf16rne(As[m * SA + (j << 1)]);
        unsigned hi = bf16rne(As[m * SA + (j << 1) + 1]);
        part[(base << 5) + idx] = lo | (hi << 16);   // coalesced full-tile write
    }
    if (tid < TM) {
        int cn = (int)As[tid * SA + 64];
        if (cn) atomicAdd(&indeg[base + tid], cn);
    }
}

// ---------------- dense finish (layer 0): sum partials + GEMM, re-zero aggb --------

__global__ __launch_bounds__(256, 4) void sage_finish_dense(
    const unsigned* __restrict__ xb, unsigned* __restrict__ aggb,
    const unsigned* __restrict__ aggc, const int* __restrict__ indeg,
    float* __restrict__ hout,
    const float* __restrict__ Wl, const float* __restrict__ bl,
    const float* __restrict__ Wr)
{
    __shared__ float As[TM * SA];
    __shared__ float Xs[TM * SA];
    __shared__ float invs[TM];

    const int tid  = threadIdx.x;
    const int base = blockIdx.x * TM;                // grid NBLK

    if (tid < TM) invs[tid] = 1.0f / (float)max(indeg[base + tid], 1);
    __syncthreads();

    for (int idx = tid; idx < TM * 32; idx += 256) {
        int m = idx >> 5, k2 = (idx & 31) << 1;
        unsigned a = aggb[(base << 5) + idx];
        unsigned b = aggc[(base << 5) + idx];
        As[m * SA + k2]     = (__uint_as_float(a << 16) +
                               __uint_as_float(b << 16)) * invs[m];
        As[m * SA + k2 + 1] = (__uint_as_float(a & 0xffff0000u) +
                               __uint_as_float(b & 0xffff0000u)) * invs[m];
        aggb[(base << 5) + idx] = 0u;                // re-zero for layer-1 push
        unsigned xw = xb[(base << 5) + idx];
        Xs[m * SA + k2]     = __uint_as_float(xw << 16);
        Xs[m * SA + k2 + 1] = __uint_as_float(xw & 0xffff0000u);
    }
    __syncthreads();

    const int j0 = (tid & 15) << 2;
    const int m0 = (tid >> 4) << 2;
    float o[4][4];
    float4 b4 = *(const float4*)&bl[j0];
    #pragma unroll
    for (int mi = 0; mi < 4; ++mi) {
        o[mi][0] = b4.x; o[mi][1] = b4.y; o[mi][2] = b4.z; o[mi][3] = b4.w;
    }
    #pragma unroll 8
    for (int k = 0; k < D; ++k) {
        float4 wl = *(const float4*)&Wl[(k << 6) + j0];
        float4 wr = *(const float4*)&Wr[(k << 6) + j0];
        #pragma unroll
        for (int mi = 0; mi < 4; ++mi) {
            float a = As[(m0 + mi) * SA + k];
            float x = Xs[(m0 + mi) * SA + k];
            o[mi][0] += a * wl.x + x * wr.x;
            o[mi][1] += a * wl.y + x * wr.y;
            o[mi][2] += a * wl.z + x * wr.z;
            o[mi][3] += a * wl.w + x * wr.w;
        }
    }
    #pragma unroll
    for (int mi = 0; mi < 4; ++mi) {
        float4 r = make_float4(fmaxf(o[mi][0], 0.f), fmaxf(o[mi][1], 0.f),
                               fmaxf(o[mi][2], 0.f), fmaxf(o[mi][3], 0.f));
        *(float4*)&hout[(base + m0 + mi) * D + j0] = r;   // relu fused
    }
}

// ---------------- push (bf16x2 pk atomics): layer 1 (~69K edges) ----------------

__global__ __launch_bounds__(256, 8) void sage_push_bf(
    const float* __restrict__ hin, const int* __restrict__ cur,
    const int* __restrict__ esp, unsigned* __restrict__ aggb, int cap)
{
    __shared__ unsigned Rs[TM * SB];  // 64 src rows, pre-packed bf16x2

    const int tid  = threadIdx.x;
    const int base = blockIdx.x * TM;
    const int lane = tid & 63;
    const int w    = tid >> 6;
    const int l5   = lane & 31;
    const int hi   = lane >> 5;

    const int e0 = blockIdx.x * cap;
    const int e1 = min(cur[blockIdx.x], e0 + cap);
    if (e0 == e1) return;

    for (int idx = tid; idx < TM * 32; idx += 256) {
        int m = idx >> 5, k = idx & 31;
        float2 v = *(const float2*)&hin[((base + m) << 6) + (k << 1)];
        Rs[m * SB + k] = bf16rne(v.x) | (bf16rne(v.y) << 16);
    }
    __syncthreads();

    const int chunk = ((e1 - e0) + 3) >> 2;
    int e = e0 + w * chunk;
    const int ee = min(e + chunk, e1);

    for (; e + 64 <= ee; e += 64) {
        int pv = esp[e + lane];
        #pragma unroll
        for (int u = 0; u < 32; ++u) {
            int p = __shfl(pv, (u << 1) + hi);
            unsigned v = Rs[(p & 63) * SB + l5];
            __builtin_amdgcn_global_atomic_fadd_v2bf16(
                (sbf2*)&aggb[((p >> 6) << 5) + l5], *(sbf2*)&v);
        }
    }
    for (; e < ee; ++e) {
        int p = esp[e];
        if (!hi) {
            unsigned v = Rs[(p & 63) * SB + l5];
            __builtin_amdgcn_global_atomic_fadd_v2bf16(
                (sbf2*)&aggb[((p >> 6) << 5) + l5], *(sbf2*)&v);
        }
    }
}

// ---------------- push (f32, exact): layer 2 into aggf ----------------

__global__ __launch_bounds__(256, 8) void sage_push_f32(
    const float* __restrict__ hin, const int* __restrict__ cur,
    const int* __restrict__ esp, float* __restrict__ agg, int cap)
{
    __shared__ float Rs[TM * SA];

    const int tid  = threadIdx.x;
    const int base = blockIdx.x * TM;
    const int lane = tid & 63;
    const int w    = tid >> 6;

    const int e0 = blockIdx.x * cap;
    const int e1 = min(cur[blockIdx.x], e0 + cap);
    if (e0 == e1) return;

    for (int idx = tid; idx < TM * D; idx += 256) {
        int m = idx >> 6, k = idx & 63;
        Rs[m * SA + k] = hin[(base << 6) + idx];
    }
    __syncthreads();

    const int chunk = ((e1 - e0) + 3) >> 2;
    int e = e0 + w * chunk;
    const int ee = min(e + chunk, e1);

    for (; e < ee; ++e) {
        int p = esp[e];
        atomicAdd(&agg[(p & 0x7fffffc0) + lane], Rs[(p & 63) * SA + lane]);
    }
}

// ---------------- finish on compacted list (layer 1: ~4.3K nodes) ----------------

__global__ __launch_bounds__(256, 4) void sage_finish_sel(
    const float* __restrict__ hin, unsigned* __restrict__ aggb,
    const int* __restrict__ indeg, const int* __restrict__ list,
    const int* __restrict__ pcount, float* __restrict__ hout,
    const float* __restrict__ Wl, const float* __restrict__ bl,
    const float* __restrict__ Wr)
{
    __shared__ float As[TM * SA];
    __shared__ float Xs[TM * SA];
    __shared__ float invs[TM];
    __shared__ int   nid[TM];

    const int cntv = *pcount;
    const int base = blockIdx.x * TM;
    if (base >= cntv) return;

    const int tid = threadIdx.x;
    if (tid < TM) {
        int n = (base + tid < cntv) ? list[base + tid] : -1;
        nid[tid]  = n;
        invs[tid] = (n >= 0) ? 1.0f / (float)max(indeg[n], 1) : 0.f;
    }
    __syncthreads();
    for (int idx = tid; idx < TM * 32; idx += 256) {
        int m = idx >> 5, k2 = idx & 31;
        int n = nid[m];
        if (n >= 0) {
            unsigned v = aggb[(n << 5) + k2];
            As[m * SA + (k2 << 1)]     = __uint_as_float(v << 16) * invs[m];
            As[m * SA + (k2 << 1) + 1] = __uint_as_float(v & 0xffff0000u) * invs[m];
        } else {
            As[m * SA + (k2 << 1)]     = 0.f;
            As[m * SA + (k2 << 1) + 1] = 0.f;
        }
    }
    for (int idx = tid; idx < TM * D; idx += 256) {
        int m = idx >> 6, k = idx & 63;
        int n = nid[m];
        Xs[m * SA + k] = (n >= 0) ? hin[n * D + k] : 0.f;
    }
    __syncthreads();

    const int j0 = (tid & 15) << 2;
    const int m0 = (tid >> 4) << 2;
    float o[4][4];
    float4 b4 = *(const float4*)&bl[j0];
    #pragma unroll
    for (int mi = 0; mi < 4; ++mi) {
        o[mi][0] = b4.x; o[mi][1] = b4.y; o[mi][2] = b4.z; o[mi][3] = b4.w;
    }
    #pragma unroll 8
    for (int k = 0; k < D; ++k) {
        float4 wl = *(const float4*)&Wl[(k << 6) + j0];
        float4 wr = *(const float4*)&Wr[(k << 6) + j0];
        #pragma unroll
        for (int mi = 0; mi < 4; ++mi) {
            float a = As[(m0 + mi) * SA + k];
            float x = Xs[(m0 + mi) * SA + k];
            o[mi][0] += a * wl.x + x * wr.x;
            o[mi][1] += a * wl.y + x * wr.y;
            o[mi][2] += a * wl.z + x * wr.z;
            o[mi][3] += a * wl.w + x * wr.w;
        }
    }
    #pragma unroll
    for (int mi = 0; mi < 4; ++mi) {
        int n = nid[m0 + mi];
        if (n >= 0) {
            float4 r = make_float4(fmaxf(o[mi][0], 0.f), fmaxf(o[mi][1], 0.f),
                                   fmaxf(o[mi][2], 0.f), fmaxf(o[mi][3], 0.f));
            *(float4*)&hout[n * D + j0] = r;
        }
    }
}

// ---------------- final layer GEMM on the 256 selected nodes (exact f32 agg) --------

__global__ __launch_bounds__(256, 3) void final_gemm_sel(
    const float* __restrict__ hin, const float* __restrict__ agg,
    const int* __restrict__ indeg, const int* __restrict__ fidx,
    const float* __restrict__ Wl, const float* __restrict__ bl,
    const float* __restrict__ Wr, float* __restrict__ out)
{
    __shared__ float As[TM * SA];
    __shared__ float Xs[TM * SA];
    __shared__ int   nid[TM];
    __shared__ float invs[TM];

    const int tid  = threadIdx.x;
    const int base = blockIdx.x * TM;

    if (tid < TM) {
        int n = fidx[base + tid];
        nid[tid]  = n;
        invs[tid] = 1.0f / (float)max(indeg[n], 1);
    }
    __syncthreads();
    for (int idx = tid; idx < TM * D; idx += 256) {
        int m = idx >> 6, k = idx & 63;
        int n = nid[m];
        As[m * SA + k] = agg[n * D + k] * invs[m];
        Xs[m * SA + k] = hin[n * D + k];
    }
    __syncthreads();

    const int j0 = (tid & 15) << 2;
    const int m0 = (tid >> 4) << 2;
    float o[4][4];
    float4 b4 = *(const float4*)&bl[j0];
    #pragma unroll
    for (int mi = 0; mi < 4; ++mi) {
        o[mi][0] = b4.x; o[mi][1] = b4.y; o[mi][2] = b4.z; o[mi][3] = b4.w;
    }
    #pragma unroll 8
    for (int k = 0; k < D; ++k) {
        float4 wl = *(const float4*)&Wl[(k << 6) + j0];
        float4 wr = *(const float4*)&Wr[(k << 6) + j0];
        #pragma unroll
        for (int mi = 0; mi < 4; ++mi) {
            float a = As[(m0 + mi) * SA + k];
            float x = Xs[(m0 + mi) * SA + k];
            o[mi][0] += a * wl.x + x * wr.x;
            o[mi][1] += a * wl.y + x * wr.y;
            o[mi][2] += a * wl.z + x * wr.z;
            o[mi][3] += a * wl.w + x * wr.w;
        }
    }
    #pragma unroll
    for (int mi = 0; mi < 4; ++mi) {
        float4 r = make_float4(o[mi][0], o[mi][1], o[mi][2], o[mi][3]);
        *(float4*)&out[(base + m0 + mi) * D + j0] = r;
    }
}

// ---------------- launch ----------------

extern "C" void kernel_launch(void* const* d_in, const int* in_sizes, int n_in,
                              void* d_out, int out_size, void* d_ws, size_t ws_size,
                              hipStream_t stream)
{
    const float* x     = (const float*)d_in[0];
    const int*   ei    = (const int*)d_in[1];
    const int*   batch = (const int*)d_in[2];
    const float* Wl0 = (const float*)d_in[3];
    const float* bl0 = (const float*)d_in[4];
    const float* Wr0 = (const float*)d_in[5];
    const float* Wl1 = (const float*)d_in[6];
    const float* bl1 = (const float*)d_in[7];
    const float* Wr1 = (const float*)d_in[8];
    const float* Wl2 = (const float*)d_in[9];
    const float* bl2 = (const float*)d_in[10];
    const float* Wr2 = (const float*)d_in[11];
    float* out = (float*)d_out;

    const int* src = ei;             // edge_index[0]
    const int* dst = ei + N_EDGES;   // edge_index[1]

    char* ws = (char*)d_ws;
    size_t off = 0;
    auto alloc = [&](size_t bytes) -> void* {
        void* p = ws + off;
        off = (off + bytes + 255) & ~(size_t)255;
        return p;
    };
    int*      cur0  = (int*)alloc(NBLK * sizeof(int));
    int*      cur1  = (int*)alloc(NBLK * sizeof(int));
    int*      cur2  = (int*)alloc(NBLK * sizeof(int));
    int*      fidx  = (int*)alloc(NG * sizeof(int));
    int*      list1 = (int*)alloc(N_NODES * sizeof(int));
    int*      esp0  = (int*)alloc((size_t)NBLK * CAP0 * sizeof(int));
    int*      esp1  = (int*)alloc((size_t)NBLK * CAP1 * sizeof(int));
    int*      esp2  = (int*)alloc((size_t)NBLK * CAP2 * sizeof(int));
    unsigned* aggb  = (unsigned*)alloc((size_t)N_NODES * 32 * sizeof(unsigned)); // bf16x2
    float*    aggf  = (float*)alloc((size_t)N_NODES * D * sizeof(float));        // layer-2 exact
    float*    h1    = (float*)alloc((size_t)N_NODES * D * sizeof(float));
    float*    h2    = (float*)alloc((size_t)N_NODES * D * sizeof(float));
    unsigned* bms   = (unsigned*)alloc((size_t)3 * BMW * sizeof(unsigned));
    int*      indeg = (int*)alloc(N_NODES * sizeof(int));
    int*      n01   = (int*)alloc(64 * sizeof(int));
    unsigned* bm0 = bms;
    unsigned* bm1 = bms + BMW;
    unsigned* bm2 = bms + 2 * BMW;
    int* n1 = n01 + 1;
    // xb (bf16 copy of x) and aggc (2nd pull partial) alias h2: both are dead
    // before sage_finish_sel writes h2.
    unsigned* xb   = (unsigned*)h2;
    unsigned* aggc = (unsigned*)h2 + (size_t)N_NODES * 32;
    (void)ws_size; (void)in_sizes; (void)n_in; (void)out_size;

    const int EB = (N_EDGES + 255) / 256;   // 5120

    init_ws<<<NB, 256, 0, stream>>>(bms, indeg, n01, cur0, cur1, cur2);
    x_to_bf16<<<N_NODES * 32 / 256, 256, 0, stream>>>((const float2*)x, xb);
    ff_mark<<<NB, 256, 0, stream>>>(batch, fidx, bm2, bm1, aggf);
    mark_srcs_bm<<<EB, 256, 0, stream>>>(src, dst, bm2, bm1, (const unsigned*)nullptr);
    mark_srcs_bm<<<EB, 256, 0, stream>>>(src, dst, bm1, bm0, bm1);
    build<<<NB, 256, 0, stream>>>(src, dst, bm0, bm1, bm2, cur0, cur1, cur2,
                                  esp0, esp1, esp2, list1, n1);

    // layer 0: K-split fire-and-forget pull (no global atomics) + dense finish GEMM
    sage_pull_l0<<<2 * NBLK, 256, 0, stream>>>(xb, cur0, esp0, indeg, aggb, aggc);
    sage_finish_dense<<<NBLK, 256, 0, stream>>>(xb, aggb, aggc, indeg, h1,
                                                Wl0, bl0, Wr0);
    // layer 1: bf16 pk push + list finish (~4.3K nodes)
    sage_push_bf     <<<NBLK, 256, 0, stream>>>(h1, cur1, esp1, aggb, CAP1);
    sage_finish_sel  <<<NBLK, 256, 0, stream>>>(h1, aggb, indeg, list1, n1,
                                                h2, Wl1, bl1, Wr1);
    // layer 2: exact f32 push into the 256 output rows + output GEMM
    sage_push_f32    <<<NBLK, 256, 0, stream>>>(h2, cur2, esp2, aggf, CAP2);
    final_gemm_sel   <<<NG / TM, 256, 0, stream>>>(h2, aggf, indeg, fidx, Wl2, bl2, Wr2, out);
}

// Round 6
// 411.807 us; speedup vs baseline: 1.3932x; 1.3932x over previous
//
#include <hip/hip_runtime.h>

#define N_NODES 81920
#define N_EDGES 1310720
#define NG 256
#define D 64
#define TM 64
#define SA 65            // f32 LDS row stride (GEMM tiles)
#define SB 33            // bf16x2 LDS row stride in push (2-way bank alias, free)
#define NB 320           // 256-thread node blocks covering N_NODES
#define NBLK 1280        // src blocks of 64 nodes
#define BMW 2560         // bitmask words (81920/32)
#define HCHUNK 4096      // edges per build workgroup (NB*HCHUNK == N_EDGES)
#define EPT 16           // edges per thread in build (HCHUNK/256)
#define CAP0 1280        // slab capacities per src block (mean 576, sigma 24)
#define CAP1 256
#define CAP2 64

typedef __attribute__((ext_vector_type(2))) short sbf2;

__device__ __forceinline__ bool tb(const unsigned* bm, int i) {
    return (bm[i >> 5] >> (i & 31)) & 1u;
}
__device__ __forceinline__ unsigned bf16rne(float f) {
    unsigned u = __float_as_uint(f);
    return (u + 0x7fffu + ((u >> 16) & 1u)) >> 16;
}

// ---------------- init: zero aggb/bitmasks/indeg/counters, cursors, x->bf16 --------

__global__ __launch_bounds__(256) void init_ws(float4* __restrict__ aggb4,
                                               unsigned* __restrict__ bms,   // 3*BMW
                                               int* __restrict__ indeg,
                                               int* __restrict__ n01,
                                               int* __restrict__ cur0,
                                               int* __restrict__ cur1,
                                               int* __restrict__ cur2,
                                               const float2* __restrict__ x2,
                                               unsigned* __restrict__ xb) {
    int t = blockIdx.x * 256 + threadIdx.x;          // grid 1280 -> 327680 threads
    float4 z = make_float4(0.f, 0.f, 0.f, 0.f);
    aggb4[t] = z;                                    // 10.5 MB bf16x2 agg
    aggb4[t + NBLK * 256] = z;
    if (t < 3 * BMW) bms[t] = 0u;
    if (t < N_NODES) indeg[t] = 0;
    if (t < 2) n01[t] = 0;
    if (t < NBLK) {
        cur0[t] = t * CAP0;
        cur1[t] = t * CAP1;
        cur2[t] = t * CAP2;
    }
    // x -> bf16x2 (2.62M words, 8 per thread, grid-stride coalesced)
    #pragma unroll
    for (int i = 0; i < 8; ++i) {
        int idx = i * (NBLK * 256) + t;
        float2 v = x2[idx];
        xb[idx] = bf16rne(v.x) | (bf16rne(v.y) << 16);
    }
}

// ---------------- graph firsts + seed bm2/bm1 + zero the 256 f32 agg rows ----------

__global__ void ff_mark(const int* __restrict__ batch, int* __restrict__ fidx,
                        unsigned* __restrict__ bm2, unsigned* __restrict__ bm1,
                        float* __restrict__ aggf) {
    int i = blockIdx.x * 256 + threadIdx.x;          // grid NB
    int b = batch[i];
    if (i == 0 || batch[i - 1] != b) {
        fidx[b] = i;
        unsigned bit = 1u << (i & 31);
        atomicOr(&bm2[i >> 5], bit);
        atomicOr(&bm1[i >> 5], bit);
        float4* r = (float4*)&aggf[i * D];           // zero this output row (layer-2 agg)
        #pragma unroll
        for (int j = 0; j < 16; ++j) r[j] = make_float4(0.f, 0.f, 0.f, 0.f);
    }
}

// mark srcs of edges with dst-bit in bmD into bmS; optional OR-copy orsrc -> bmS
__global__ void mark_srcs_bm(const int* __restrict__ src, const int* __restrict__ dst,
                             const unsigned* __restrict__ bmD, unsigned* __restrict__ bmS,
                             const unsigned* __restrict__ orsrc) {
    if (orsrc && blockIdx.x == 0) {
        for (int w = threadIdx.x; w < BMW; w += 256)
            if (orsrc[w]) atomicOr(&bmS[w], orsrc[w]);
    }
    int e = blockIdx.x * 256 + threadIdx.x;
    if (e < N_EDGES && tb(bmD, dst[e])) {
        int s = src[e];
        atomicOr(&bmS[s >> 5], 1u << (s & 31));
    }
}

// ---------------- build: ONE edge stream, register-carried ranks, slab bucketing ----
// Layer 0 (93% of masked edges): LDS histogram + bulk reserve + register placement,
// bucketed by SRC block (push format pk = (d<<6)|(s&63)).
// Layers 1/2 (rare): direct global cursor atomics. + indeg + list1 compaction.

__global__ __launch_bounds__(256) void build(const int* __restrict__ src,
                                             const int* __restrict__ dst,
                                             const unsigned* __restrict__ bm0,
                                             const unsigned* __restrict__ bm1,
                                             const unsigned* __restrict__ bm2,
                                             int* __restrict__ cur0,
                                             int* __restrict__ cur1,
                                             int* __restrict__ cur2,
                                             int* __restrict__ esp0,
                                             int* __restrict__ esp1,
                                             int* __restrict__ esp2,
                                             int* __restrict__ indeg,
                                             int* __restrict__ list1,
                                             int* __restrict__ n1) {
    __shared__ int h0[NBLK];      // per-src-block count
    __shared__ int b0[NBLK];      // reserved base per src block
    const int tid = threadIdx.x;
    const int e0  = blockIdx.x * HCHUNK;             // grid NB (320)

    for (int i = tid; i < NBLK; i += 256) h0[i] = 0;

    // list1 compaction for this WG's 256-node chunk (independent)
    {
        int i = blockIdx.x * 256 + tid;
        int lane = tid & 63;
        bool p1 = tb(bm1, i);
        unsigned long long b1 = __ballot(p1);
        int lt = __popcll(b1 & ((1ull << lane) - 1));
        int base = 0;
        if (lane == 0 && b1) base = atomicAdd(n1, __popcll(b1));
        base = __shfl(base, 0);
        if (p1) list1[base + lt] = i;
    }
    __syncthreads();

    int pk_r[EPT];
    int sb_r[EPT];
    int rk_r[EPT];

    // pass A: stream edges once; count L0 in LDS, carry ranks in registers;
    // place rare L1/L2 directly; indeg fire-and-forget
    #pragma unroll
    for (int j = 0; j < EPT; ++j) {
        int e = e0 + j * 256 + tid;                  // coalesced
        int d = dst[e];
        sb_r[j] = -1;
        if (tb(bm0, d)) {
            int s  = src[e];
            int sb = s >> 6;
            int pk = (d << 6) | (s & 63);
            pk_r[j] = pk;
            sb_r[j] = sb;
            rk_r[j] = atomicAdd(&h0[sb], 1);         // LDS
            atomicAdd(&indeg[d], 1);                 // global fire-and-forget
            if (tb(bm1, d)) {
                int p1 = atomicAdd(&cur1[sb], 1);    // rare (9%)
                if (p1 < sb * CAP1 + CAP1) esp1[p1] = pk;
                if (tb(bm2, d)) {
                    int p2 = atomicAdd(&cur2[sb], 1); // very rare (0.7%)
                    if (p2 < sb * CAP2 + CAP2) esp2[p2] = pk;
                }
            }
        }
    }
    __syncthreads();

    // bulk-reserve layer-0 slab chunks
    for (int i = tid; i < NBLK; i += 256) {
        int c = h0[i];
        b0[i] = c ? atomicAdd(&cur0[i], c) : 0;
    }
    __syncthreads();

    // pass B: place layer-0 edges from registers (no re-stream, no second LDS atomic)
    #pragma unroll
    for (int j = 0; j < EPT; ++j) {
        int sb = sb_r[j];
        if (sb >= 0) {
            int pos = b0[sb] + rk_r[j];
            if (pos < sb * CAP0 + CAP0) esp0[pos] = pk_r[j];
        }
    }
}

// ---------------- push L0 (bf16x2 pk atomics) from pre-packed xb ----------------
// 930 GB/s atomic-fabric path (measured r0: 99 us). Staging is a straight copy.

__global__ __launch_bounds__(256, 8) void sage_push_bf_pre(
    const unsigned* __restrict__ xb, const int* __restrict__ cur,
    const int* __restrict__ esp, unsigned* __restrict__ aggb, int cap)
{
    __shared__ unsigned Rs[TM * SB];  // 64 src rows, pre-packed bf16x2

    const int tid  = threadIdx.x;
    const int base = blockIdx.x * TM;
    const int lane = tid & 63;
    const int w    = tid >> 6;
    const int l5   = lane & 31;
    const int hi   = lane >> 5;

    const int e0 = blockIdx.x * cap;
    const int e1 = min(cur[blockIdx.x], e0 + cap);
    if (e0 == e1) return;

    for (int idx = tid; idx < TM * 32; idx += 256) {
        int m = idx >> 5, k = idx & 31;
        Rs[m * SB + k] = xb[(base << 5) + idx];      // coalesced copy
    }
    __syncthreads();

    const int chunk = ((e1 - e0) + 3) >> 2;
    int e = e0 + w * chunk;
    const int ee = min(e + chunk, e1);

    for (; e + 64 <= ee; e += 64) {
        int pv = esp[e + lane];
        #pragma unroll
        for (int u = 0; u < 32; ++u) {
            int p = __shfl(pv, (u << 1) + hi);
            unsigned v = Rs[(p & 63) * SB + l5];
            __builtin_amdgcn_global_atomic_fadd_v2bf16(
                (sbf2*)&aggb[((p >> 6) << 5) + l5], *(sbf2*)&v);
        }
    }
    for (; e < ee; ++e) {
        int p = esp[e];
        if (!hi) {
            unsigned v = Rs[(p & 63) * SB + l5];
            __builtin_amdgcn_global_atomic_fadd_v2bf16(
                (sbf2*)&aggb[((p >> 6) << 5) + l5], *(sbf2*)&v);
        }
    }
}

// ---------------- push (bf16x2 pk atomics) from f32 rows: layer 1 ----------------

__global__ __launch_bounds__(256, 8) void sage_push_bf(
    const float* __restrict__ hin, const int* __restrict__ cur,
    const int* __restrict__ esp, unsigned* __restrict__ aggb, int cap)
{
    __shared__ unsigned Rs[TM * SB];  // 64 src rows, pre-packed bf16x2

    const int tid  = threadIdx.x;
    const int base = blockIdx.x * TM;
    const int lane = tid & 63;
    const int w    = tid >> 6;
    const int l5   = lane & 31;
    const int hi   = lane >> 5;

    const int e0 = blockIdx.x * cap;
    const int e1 = min(cur[blockIdx.x], e0 + cap);
    if (e0 == e1) return;

    for (int idx = tid; idx < TM * 32; idx += 256) {
        int m = idx >> 5, k = idx & 31;
        float2 v = *(const float2*)&hin[((base + m) << 6) + (k << 1)];
        Rs[m * SB + k] = bf16rne(v.x) | (bf16rne(v.y) << 16);
    }
    __syncthreads();

    const int chunk = ((e1 - e0) + 3) >> 2;
    int e = e0 + w * chunk;
    const int ee = min(e + chunk, e1);

    for (; e + 64 <= ee; e += 64) {
        int pv = esp[e + lane];
        #pragma unroll
        for (int u = 0; u < 32; ++u) {
            int p = __shfl(pv, (u << 1) + hi);
            unsigned v = Rs[(p & 63) * SB + l5];
            __builtin_amdgcn_global_atomic_fadd_v2bf16(
                (sbf2*)&aggb[((p >> 6) << 5) + l5], *(sbf2*)&v);
        }
    }
    for (; e < ee; ++e) {
        int p = esp[e];
        if (!hi) {
            unsigned v = Rs[(p & 63) * SB + l5];
            __builtin_amdgcn_global_atomic_fadd_v2bf16(
                (sbf2*)&aggb[((p >> 6) << 5) + l5], *(sbf2*)&v);
        }
    }
}

// ---------------- push (f32, exact): layer 2 into aggf ----------------

__global__ __launch_bounds__(256, 8) void sage_push_f32(
    const float* __restrict__ hin, const int* __restrict__ cur,
    const int* __restrict__ esp, float* __restrict__ agg, int cap)
{
    __shared__ float Rs[TM * SA];

    const int tid  = threadIdx.x;
    const int base = blockIdx.x * TM;
    const int lane = tid & 63;
    const int w    = tid >> 6;

    const int e0 = blockIdx.x * cap;
    const int e1 = min(cur[blockIdx.x], e0 + cap);
    if (e0 == e1) return;

    for (int idx = tid; idx < TM * D; idx += 256) {
        int m = idx >> 6, k = idx & 63;
        Rs[m * SA + k] = hin[(base << 6) + idx];
    }
    __syncthreads();

    const int chunk = ((e1 - e0) + 3) >> 2;
    int e = e0 + w * chunk;
    const int ee = min(e + chunk, e1);

    for (; e < ee; ++e) {
        int p = esp[e];
        atomicAdd(&agg[(p & 0x7fffffc0) + lane], Rs[(p & 63) * SA + lane]);
    }
}

// ---------------- dense finish (layer 0): all nodes, fully coalesced ----------------

__global__ __launch_bounds__(256, 4) void sage_finish_dense(
    const unsigned* __restrict__ xb, unsigned* __restrict__ aggb,
    const int* __restrict__ indeg, float* __restrict__ hout,
    const float* __restrict__ Wl, const float* __restrict__ bl,
    const float* __restrict__ Wr)
{
    __shared__ float As[TM * SA];
    __shared__ float Xs[TM * SA];
    __shared__ float invs[TM];

    const int tid  = threadIdx.x;
    const int base = blockIdx.x * TM;                // grid NBLK

    if (tid < TM) invs[tid] = 1.0f / (float)max(indeg[base + tid], 1);
    for (int idx = tid; idx < TM * 32; idx += 256) { // unpack bf16x2 agg + re-zero
        int m = idx >> 5, k2 = (idx & 31) << 1;
        unsigned v = aggb[(base << 5) + idx];
        As[m * SA + k2]     = __uint_as_float(v << 16);
        As[m * SA + k2 + 1] = __uint_as_float(v & 0xffff0000u);
        aggb[(base << 5) + idx] = 0u;                // re-zero for layer-1 push
        unsigned xw = xb[(base << 5) + idx];
        Xs[m * SA + k2]     = __uint_as_float(xw << 16);
        Xs[m * SA + k2 + 1] = __uint_as_float(xw & 0xffff0000u);
    }
    __syncthreads();
    for (int idx = tid; idx < TM * D; idx += 256) {
        int m = idx >> 6, k = idx & 63;
        As[m * SA + k] *= invs[m];
    }
    __syncthreads();

    const int j0 = (tid & 15) << 2;
    const int m0 = (tid >> 4) << 2;
    float o[4][4];
    float4 b4 = *(const float4*)&bl[j0];
    #pragma unroll
    for (int mi = 0; mi < 4; ++mi) {
        o[mi][0] = b4.x; o[mi][1] = b4.y; o[mi][2] = b4.z; o[mi][3] = b4.w;
    }
    #pragma unroll 8
    for (int k = 0; k < D; ++k) {
        float4 wl = *(const float4*)&Wl[(k << 6) + j0];
        float4 wr = *(const float4*)&Wr[(k << 6) + j0];
        #pragma unroll
        for (int mi = 0; mi < 4; ++mi) {
            float a = As[(m0 + mi) * SA + k];
            float x = Xs[(m0 + mi) * SA + k];
            o[mi][0] += a * wl.x + x * wr.x;
            o[mi][1] += a * wl.y + x * wr.y;
            o[mi][2] += a * wl.z + x * wr.z;
            o[mi][3] += a * wl.w + x * wr.w;
        }
    }
    #pragma unroll
    for (int mi = 0; mi < 4; ++mi) {
        float4 r = make_float4(fmaxf(o[mi][0], 0.f), fmaxf(o[mi][1], 0.f),
                               fmaxf(o[mi][2], 0.f), fmaxf(o[mi][3], 0.f));
        *(float4*)&hout[(base + m0 + mi) * D + j0] = r;   // relu fused
    }
}

// ---------------- finish on compacted list (layer 1: ~4.3K nodes) ----------------

__global__ __launch_bounds__(256, 4) void sage_finish_sel(
    const float* __restrict__ hin, unsigned* __restrict__ aggb,
    const int* __restrict__ indeg, const int* __restrict__ list,
    const int* __restrict__ pcount, float* __restrict__ hout,
    const float* __restrict__ Wl, const float* __restrict__ bl,
    const float* __restrict__ Wr)
{
    __shared__ float As[TM * SA];
    __shared__ float Xs[TM * SA];
    __shared__ float invs[TM];
    __shared__ int   nid[TM];

    const int cntv = *pcount;
    const int base = blockIdx.x * TM;
    if (base >= cntv) return;

    const int tid = threadIdx.x;
    if (tid < TM) {
        int n = (base + tid < cntv) ? list[base + tid] : -1;
        nid[tid]  = n;
        invs[tid] = (n >= 0) ? 1.0f / (float)max(indeg[n], 1) : 0.f;
    }
    __syncthreads();
    for (int idx = tid; idx < TM * 32; idx += 256) {
        int m = idx >> 5, k2 = idx & 31;
        int n = nid[m];
        if (n >= 0) {
            unsigned v = aggb[(n << 5) + k2];
            As[m * SA + (k2 << 1)]     = __uint_as_float(v << 16) * invs[m];
            As[m * SA + (k2 << 1) + 1] = __uint_as_float(v & 0xffff0000u) * invs[m];
        } else {
            As[m * SA + (k2 << 1)]     = 0.f;
            As[m * SA + (k2 << 1) + 1] = 0.f;
        }
    }
    for (int idx = tid; idx < TM * D; idx += 256) {
        int m = idx >> 6, k = idx & 63;
        int n = nid[m];
        Xs[m * SA + k] = (n >= 0) ? hin[n * D + k] : 0.f;
    }
    __syncthreads();

    const int j0 = (tid & 15) << 2;
    const int m0 = (tid >> 4) << 2;
    float o[4][4];
    float4 b4 = *(const float4*)&bl[j0];
    #pragma unroll
    for (int mi = 0; mi < 4; ++mi) {
        o[mi][0] = b4.x; o[mi][1] = b4.y; o[mi][2] = b4.z; o[mi][3] = b4.w;
    }
    #pragma unroll 8
    for (int k = 0; k < D; ++k) {
        float4 wl = *(const float4*)&Wl[(k << 6) + j0];
        float4 wr = *(const float4*)&Wr[(k << 6) + j0];
        #pragma unroll
        for (int mi = 0; mi < 4; ++mi) {
            float a = As[(m0 + mi) * SA + k];
            float x = Xs[(m0 + mi) * SA + k];
            o[mi][0] += a * wl.x + x * wr.x;
            o[mi][1] += a * wl.y + x * wr.y;
            o[mi][2] += a * wl.z + x * wr.z;
            o[mi][3] += a * wl.w + x * wr.w;
        }
    }
    #pragma unroll
    for (int mi = 0; mi < 4; ++mi) {
        int n = nid[m0 + mi];
        if (n >= 0) {
            float4 r = make_float4(fmaxf(o[mi][0], 0.f), fmaxf(o[mi][1], 0.f),
                                   fmaxf(o[mi][2], 0.f), fmaxf(o[mi][3], 0.f));
            *(float4*)&hout[n * D + j0] = r;
        }
    }
}

// ---------------- final layer GEMM on the 256 selected nodes (exact f32 agg) --------

__global__ __launch_bounds__(256, 3) void final_gemm_sel(
    const float* __restrict__ hin, const float* __restrict__ agg,
    const int* __restrict__ indeg, const int* __restrict__ fidx,
    const float* __restrict__ Wl, const float* __restrict__ bl,
    const float* __restrict__ Wr, float* __restrict__ out)
{
    __shared__ float As[TM * SA];
    __shared__ float Xs[TM * SA];
    __shared__ int   nid[TM];
    __shared__ float invs[TM];

    const int tid  = threadIdx.x;
    const int base = blockIdx.x * TM;

    if (tid < TM) {
        int n = fidx[base + tid];
        nid[tid]  = n;
        invs[tid] = 1.0f / (float)max(indeg[n], 1);
    }
    __syncthreads();
    for (int idx = tid; idx < TM * D; idx += 256) {
        int m = idx >> 6, k = idx & 63;
        int n = nid[m];
        As[m * SA + k] = agg[n * D + k] * invs[m];
        Xs[m * SA + k] = hin[n * D + k];
    }
    __syncthreads();

    const int j0 = (tid & 15) << 2;
    const int m0 = (tid >> 4) << 2;
    float o[4][4];
    float4 b4 = *(const float4*)&bl[j0];
    #pragma unroll
    for (int mi = 0; mi < 4; ++mi) {
        o[mi][0] = b4.x; o[mi][1] = b4.y; o[mi][2] = b4.z; o[mi][3] = b4.w;
    }
    #pragma unroll 8
    for (int k = 0; k < D; ++k) {
        float4 wl = *(const float4*)&Wl[(k << 6) + j0];
        float4 wr = *(const float4*)&Wr[(k << 6) + j0];
        #pragma unroll
        for (int mi = 0; mi < 4; ++mi) {
            float a = As[(m0 + mi) * SA + k];
            float x = Xs[(m0 + mi) * SA + k];
            o[mi][0] += a * wl.x + x * wr.x;
            o[mi][1] += a * wl.y + x * wr.y;
            o[mi][2] += a * wl.z + x * wr.z;
            o[mi][3] += a * wl.w + x * wr.w;
        }
    }
    #pragma unroll
    for (int mi = 0; mi < 4; ++mi) {
        float4 r = make_float4(o[mi][0], o[mi][1], o[mi][2], o[mi][3]);
        *(float4*)&out[(base + m0 + mi) * D + j0] = r;
    }
}

// ---------------- launch ----------------

extern "C" void kernel_launch(void* const* d_in, const int* in_sizes, int n_in,
                              void* d_out, int out_size, void* d_ws, size_t ws_size,
                              hipStream_t stream)
{
    const float* x     = (const float*)d_in[0];
    const int*   ei    = (const int*)d_in[1];
    const int*   batch = (const int*)d_in[2];
    const float* Wl0 = (const float*)d_in[3];
    const float* bl0 = (const float*)d_in[4];
    const float* Wr0 = (const float*)d_in[5];
    const float* Wl1 = (const float*)d_in[6];
    const float* bl1 = (const float*)d_in[7];
    const float* Wr1 = (const float*)d_in[8];
    const float* Wl2 = (const float*)d_in[9];
    const float* bl2 = (const float*)d_in[10];
    const float* Wr2 = (const float*)d_in[11];
    float* out = (float*)d_out;

    const int* src = ei;             // edge_index[0]
    const int* dst = ei + N_EDGES;   // edge_index[1]

    char* ws = (char*)d_ws;
    size_t off = 0;
    auto alloc = [&](size_t bytes) -> void* {
        void* p = ws + off;
        off = (off + bytes + 255) & ~(size_t)255;
        return p;
    };
    int*      cur0  = (int*)alloc(NBLK * sizeof(int));
    int*      cur1  = (int*)alloc(NBLK * sizeof(int));
    int*      cur2  = (int*)alloc(NBLK * sizeof(int));
    int*      fidx  = (int*)alloc(NG * sizeof(int));
    int*      list1 = (int*)alloc(N_NODES * sizeof(int));
    int*      esp0  = (int*)alloc((size_t)NBLK * CAP0 * sizeof(int));
    int*      esp1  = (int*)alloc((size_t)NBLK * CAP1 * sizeof(int));
    int*      esp2  = (int*)alloc((size_t)NBLK * CAP2 * sizeof(int));
    unsigned* aggb  = (unsigned*)alloc((size_t)N_NODES * 32 * sizeof(unsigned)); // bf16x2
    float*    aggf  = (float*)alloc((size_t)N_NODES * D * sizeof(float));        // layer-2 exact
    float*    h1    = (float*)alloc((size_t)N_NODES * D * sizeof(float));
    float*    h2    = (float*)alloc((size_t)N_NODES * D * sizeof(float));
    unsigned* bms   = (unsigned*)alloc((size_t)3 * BMW * sizeof(unsigned));
    int*      indeg = (int*)alloc(N_NODES * sizeof(int));
    int*      n01   = (int*)alloc(64 * sizeof(int));
    unsigned* bm0 = bms;
    unsigned* bm1 = bms + BMW;
    unsigned* bm2 = bms + 2 * BMW;
    int* n1 = n01 + 1;
    // xb (bf16x2 copy of x, 10.5 MB) aliases h2: h2 is dead until sage_finish_sel,
    // and xb's last read is sage_finish_dense (validated r4/r5).
    unsigned* xb = (unsigned*)h2;
    (void)ws_size; (void)in_sizes; (void)n_in; (void)out_size;

    const int EB = (N_EDGES + 255) / 256;   // 5120

    init_ws<<<NBLK, 256, 0, stream>>>((float4*)aggb, bms, indeg, n01,
                                      cur0, cur1, cur2, (const float2*)x, xb);
    ff_mark<<<NB, 256, 0, stream>>>(batch, fidx, bm2, bm1, aggf);
    mark_srcs_bm<<<EB, 256, 0, stream>>>(src, dst, bm2, bm1, (const unsigned*)nullptr);
    mark_srcs_bm<<<EB, 256, 0, stream>>>(src, dst, bm1, bm0, bm1);
    build<<<NB, 256, 0, stream>>>(src, dst, bm0, bm1, bm2, cur0, cur1, cur2,
                                  esp0, esp1, esp2, indeg, list1, n1);

    // layer 0: bf16 pk push (atomic-fabric path, ~930 GB/s) + dense finish
    sage_push_bf_pre <<<NBLK, 256, 0, stream>>>(xb, cur0, esp0, aggb, CAP0);
    sage_finish_dense<<<NBLK, 256, 0, stream>>>(xb, aggb, indeg, h1, Wl0, bl0, Wr0);
    // layer 1: bf16 pk push + list finish (~4.3K nodes)
    sage_push_bf     <<<NBLK, 256, 0, stream>>>(h1, cur1, esp1, aggb, CAP1);
    sage_finish_sel  <<<NBLK, 256, 0, stream>>>(h1, aggb, indeg, list1, n1,
                                                h2, Wl1, bl1, Wr1);
    // layer 2: exact f32 push into the 256 output rows + output GEMM
    sage_push_f32    <<<NBLK, 256, 0, stream>>>(h2, cur2, esp2, aggf, CAP2);
    final_gemm_sel   <<<NG / TM, 256, 0, stream>>>(h2, aggf, indeg, fidx, Wl2, bl2, Wr2, out);
}